// Round 6
// baseline (49.411 us; speedup 1.0000x reference)
//
#include <hip/hip_runtime.h>

// Problem: B=4, N=384, DX=2, DR=128, H=128, DOUT=64
// out[b,n,m,o] = relu( (x_ctx[b,n]-x_ctx[b,m]) @ W1[0:2] + r[b] @ W1[2:130] + b1 ) @ W2 + b2
//
// Round-6: deep store pipelining. Diagnosis of R4/R5 neutrality: both drain
// vmcnt to ~0 every tile (R4: WAR on reused store-data regs; R5: barrier's
// implicit vmcnt(0) drain) -> stores never pipeline, 3.7 TB/s effective.
// Changes:
//   - NO barrier in main loop, NO LDS transpose. Wave owns o in [32w,32w+32)
//     and stores D directly from acc: 16x 64B full-line segments per instr
//     (R3 showed finer coalescing is neutral).
//   - Double-banked accumulators (A/B alternate per m-tile): WAR waitcnt sits
//     at vmcnt>=2, ~2 tiles of stores in flight per wave at all times.
//   - W1 pair packed f16 + v_dot2_f32_f16 (1 instr/k, f32 accum): -32 VGPR,
//     target 3 waves/SIMD (12 waves/CU).
//   - c[b,:] recomputed per block (identical arithmetic -> deterministic).

typedef __attribute__((ext_vector_type(8))) __bf16 bf16x8;
typedef __attribute__((ext_vector_type(4))) float f32x4;
typedef __attribute__((ext_vector_type(2))) float f32x2;
typedef _Float16 half_t;
typedef __attribute__((ext_vector_type(2))) half_t half2_t;

#if __has_builtin(__builtin_amdgcn_fdot2)
#define FDOT2(a, b, c) __builtin_amdgcn_fdot2((a), (b), (c), false)
#else
#define FDOT2(a, b, c) fmaf((float)(a)[0], (float)(b)[0], \
                       fmaf((float)(a)[1], (float)(b)[1], (c)))
#endif

#define B_    4
#define N_    384
#define H_    128
#define DOUT_ 64

__global__ __launch_bounds__(128, 3) void te_fused(
    const float* __restrict__ r, const float* __restrict__ xctx,
    const float* __restrict__ W1, const float* __restrict__ b1,
    const float* __restrict__ W2, const float* __restrict__ b2,
    float* __restrict__ out)
{
    __shared__ __align__(16) float xs[N_ * 2];   // 3 KB   x_ctx[b]
    __shared__ __align__(16) float cs[H_];       // 0.5 KB c[b,:]

    const int tid  = threadIdx.x;
    const int w    = tid >> 6, lane = tid & 63;
    const int g    = lane >> 4, rl = lane & 15;

    const int bid = blockIdx.x;
    const int b = bid / N_, n = bid - b * N_;

    // ---- c[k] = b1[k] + sum_d r[b,d] * W1[2+d,k]  (thread k = tid) ----
    {
        float acc = b1[tid];
        const float* wc = W1 + 2 * H_ + tid;
        const float* rb = r + b * 128;
        #pragma unroll 8
        for (int d = 0; d < 128; ++d) acc = fmaf(rb[d], wc[d * H_], acc);
        cs[tid] = acc;
    }
    // ---- stage x_ctx[b]: 768 floats ----
    {
        const float* xb = xctx + b * (N_ * 2);
        *reinterpret_cast<f32x4*>(&xs[tid * 4]) =
            *reinterpret_cast<const f32x4*>(xb + tid * 4);
        if (tid < 64)
            *reinterpret_cast<f32x4*>(&xs[512 + tid * 4]) =
                *reinterpret_cast<const f32x4*>(xb + 512 + tid * 4);
    }

    // ---- W2^T fragments for this wave's o-slice [32w, 32w+32) ----
    // A-frag row = rl; elem jj -> kk = ks*32 + (jj>=4)*16 + g*4 + (jj&3)
    bf16x8 w2f[2][4];
    #pragma unroll
    for (int ot = 0; ot < 2; ++ot) {
        const float* wp = W2 + w * 32 + ot * 16 + rl;   // + kk*64
        #pragma unroll
        for (int ks = 0; ks < 4; ++ks)
            #pragma unroll
            for (int jj = 0; jj < 8; ++jj) {
                const int kk = ks * 32 + ((jj >> 2) << 4) + (g << 2) + (jj & 3);
                w2f[ot][ks][jj] = (__bf16)wp[kk * DOUT_];
            }
    }

    // ---- packed f16 W1 pairs: w1p[ks][hh][j] = (W1[0][kk], W1[1][kk]) ----
    half2_t w1p[4][2][4];
    #pragma unroll
    for (int ks = 0; ks < 4; ++ks)
        #pragma unroll
        for (int hh = 0; hh < 2; ++hh) {
            const int kk0 = ks * 32 + hh * 16 + (g << 2);
            const f32x4 a0 = *reinterpret_cast<const f32x4*>(W1 + kk0);
            const f32x4 a1 = *reinterpret_cast<const f32x4*>(W1 + H_ + kk0);
            #pragma unroll
            for (int j = 0; j < 4; ++j)
                w1p[ks][hh][j] = half2_t{(half_t)a0[j], (half_t)a1[j]};
        }

    // ---- b2 fragments ----
    f32x4 b2f[2];
    #pragma unroll
    for (int ot = 0; ot < 2; ++ot)
        b2f[ot] = *reinterpret_cast<const f32x4*>(b2 + w * 32 + ot * 16 + (g << 2));

    __syncthreads();   // xs + cs ready (only barrier in the kernel)

    f32x4 cf[4][2];
    #pragma unroll
    for (int ks = 0; ks < 4; ++ks)
        #pragma unroll
        for (int hh = 0; hh < 2; ++hh)
            cf[ks][hh] = *reinterpret_cast<const f32x4*>(&cs[ks * 32 + hh * 16 + (g << 2)]);

    const float x0n = xs[2 * n], x1n = xs[2 * n + 1];
    float* const outn = out + ((size_t)(b * N_ + n)) * (N_ * DOUT_) + w * 32;

    // One 16-m tile: h-preact via dot2, 8 MFMA, 2 direct f32x4 stores.
    auto tile = [&](int mt, f32x4& A0, f32x4& A1) {
        const int m = mt * 16 + rl;
        const f32x2 xp = *reinterpret_cast<const f32x2*>(&xs[2 * m]);
        const half2_t dxp = {(half_t)(x0n - xp[0]), (half_t)(x1n - xp[1])};

        bf16x8 hf[4];
        #pragma unroll
        for (int ks = 0; ks < 4; ++ks)
            #pragma unroll
            for (int hh = 0; hh < 2; ++hh)
                #pragma unroll
                for (int j = 0; j < 4; ++j) {
                    float hp = FDOT2(dxp, w1p[ks][hh][j], cf[ks][hh][j]);
                    hf[ks][hh * 4 + j] = (__bf16)(hp > 0.f ? hp : 0.f);
                }

        A0 = __builtin_amdgcn_mfma_f32_16x16x32_bf16(w2f[0][0], hf[0], b2f[0], 0, 0, 0);
        A1 = __builtin_amdgcn_mfma_f32_16x16x32_bf16(w2f[1][0], hf[0], b2f[1], 0, 0, 0);
        #pragma unroll
        for (int ks = 1; ks < 4; ++ks) {
            A0 = __builtin_amdgcn_mfma_f32_16x16x32_bf16(w2f[0][ks], hf[ks], A0, 0, 0, 0);
            A1 = __builtin_amdgcn_mfma_f32_16x16x32_bf16(w2f[1][ks], hf[ks], A1, 0, 0, 0);
        }

        // D[row=g*4+reg][col=rl]: o = 32w + ot*16 + g*4 + reg, m = mt*16+rl.
        float* onp = outn + mt * (16 * DOUT_) + rl * DOUT_ + (g << 2);
        *reinterpret_cast<f32x4*>(onp)      = A0;
        *reinterpret_cast<f32x4*>(onp + 16) = A1;
    };

    // Double-banked: consecutive tiles use distinct acc regs -> the WAR
    // waitcnt before a bank's next MFMA allows the other bank's 2 stores
    // to remain in flight (vmcnt>=2 at all times, never a full drain).
    f32x4 aA0, aA1, aB0, aB1;
    for (int mt2 = 0; mt2 < 12; ++mt2) {
        tile(2 * mt2,     aA0, aA1);
        tile(2 * mt2 + 1, aB0, aB1);
    }
}

extern "C" void kernel_launch(void* const* d_in, const int* in_sizes, int n_in,
                              void* d_out, int out_size, void* d_ws, size_t ws_size,
                              hipStream_t stream)
{
    const float* r    = (const float*)d_in[0];
    const float* xctx = (const float*)d_in[1];
    // d_in[2] = y_ctx (unused), d_in[3] = x_trg (unused)
    const float* W1 = (const float*)d_in[4];
    const float* b1 = (const float*)d_in[5];
    const float* W2 = (const float*)d_in[6];
    const float* b2 = (const float*)d_in[7];
    float* out = (float*)d_out;

    hipLaunchKernelGGL(te_fused, dim3(B_ * N_), dim3(128), 0, stream,
                       r, xctx, W1, b1, W2, b2, out);
}